// Round 1
// baseline (290.271 us; speedup 1.0000x reference)
//
#include <hip/hip_runtime.h>
#include <math.h>

#define EMB_DIM 512
#define GAMMA_F 12.0f

// ---------------------------------------------------------------------------
// Kernel 1: build rotated query embeddings.
//   q[0 .. B*512-1]          = re_e
//   q[B*512 .. 2*B*512-1]    = im_e
// One thread per (b, j), B*512 threads total.
// ---------------------------------------------------------------------------
__global__ void query_kernel(const int* __restrict__ all_h,
                             const int* __restrict__ all_r,
                             const float* __restrict__ eemb,
                             const float* __restrict__ remb,
                             float* __restrict__ q, int B)
{
    int tid = blockIdx.x * blockDim.x + threadIdx.x;
    if (tid >= B * EMB_DIM) return;
    int b = tid >> 9;          // / 512
    int j = tid & (EMB_DIM - 1);
    int h = all_h[b];
    int r = all_r[b];
    float re_h = eemb[(size_t)h * (2 * EMB_DIM) + j];
    float im_h = eemb[(size_t)h * (2 * EMB_DIM) + EMB_DIM + j];
    // phase = remb / (PHASE_RANGE / pi),  PHASE_RANGE = (gamma+2)/d = 14/512
    const float SCALE = (float)(M_PI * (double)EMB_DIM / 14.0);
    float phase = remb[r * EMB_DIM + j] * SCALE;
    float s, c;
    sincosf(phase, &s, &c);
    q[b * EMB_DIM + j]                = re_h * c - im_h * s;
    q[B * EMB_DIM + b * EMB_DIM + j]  = re_h * s + im_h * c;
}

// ---------------------------------------------------------------------------
// Kernel 2: distances to all entities.
// One wave (64 lanes) per entity row, grid-stride.
//   b = lane & 7   -> which query (B=8)
//   j = lane >> 3  -> which d-octant; lane covers d = t*32 + j*4 + {0..3}
// Each lane holds its query fragment (64 re + 64 im) in registers.
// Row loads: 8 distinct float4 per instruction (128 contiguous B), each
// requested by the 8 b-lanes -> merged by the TA, full cacheline use.
// Reduction across j (lanes differing in bits 3..5): 3 shfl_xor.
// ---------------------------------------------------------------------------
__global__ __launch_bounds__(256, 2) void score_kernel(
    const float* __restrict__ eemb,
    const float* __restrict__ q,
    float* __restrict__ out,
    int N)
{
    const int lane  = threadIdx.x & 63;
    const int wid   = threadIdx.x >> 6;
    const int gwave = blockIdx.x * 4 + wid;
    const int nwaves = gridDim.x * 4;
    const int b = lane & 7;
    const int j = lane >> 3;

    // Load this lane's query fragment into registers (one-time cost).
    float4 qr[16], qi[16];
    const float* qre = q + b * EMB_DIM + j * 4;
    const float* qim = qre + 8 * EMB_DIM;   // B=8
    #pragma unroll
    for (int t = 0; t < 16; ++t) {
        qr[t] = *(const float4*)(qre + t * 32);
        qi[t] = *(const float4*)(qim + t * 32);
    }

    for (int n = gwave; n < N; n += nwaves) {
        const float* row = eemb + (size_t)n * (2 * EMB_DIM) + j * 4;
        float a0 = 0.f, a1 = 0.f, a2 = 0.f, a3 = 0.f;
        #pragma unroll
        for (int t = 0; t < 16; ++t) {
            float4 er = *(const float4*)(row + t * 32);
            float4 ei = *(const float4*)(row + EMB_DIM + t * 32);
            float dx, dy;
            dx = qr[t].x - er.x; dy = qi[t].x - ei.x;
            a0 += __builtin_amdgcn_sqrtf(fmaf(dx, dx, dy * dy));
            dx = qr[t].y - er.y; dy = qi[t].y - ei.y;
            a1 += __builtin_amdgcn_sqrtf(fmaf(dx, dx, dy * dy));
            dx = qr[t].z - er.z; dy = qi[t].z - ei.z;
            a2 += __builtin_amdgcn_sqrtf(fmaf(dx, dx, dy * dy));
            dx = qr[t].w - er.w; dy = qi[t].w - ei.w;
            a3 += __builtin_amdgcn_sqrtf(fmaf(dx, dx, dy * dy));
        }
        float v = (a0 + a1) + (a2 + a3);
        // sum across the 8 j-groups (lane bits 3..5)
        v += __shfl_xor(v, 8);
        v += __shfl_xor(v, 16);
        v += __shfl_xor(v, 32);
        if (j == 0) out[(size_t)b * N + n] = GAMMA_F - v;
    }
}

extern "C" void kernel_launch(void* const* d_in, const int* in_sizes, int n_in,
                              void* d_out, int out_size, void* d_ws, size_t ws_size,
                              hipStream_t stream) {
    const int*   all_h = (const int*)d_in[0];
    const int*   all_r = (const int*)d_in[1];
    const float* eemb  = (const float*)d_in[2];
    const float* remb  = (const float*)d_in[3];
    float* out = (float*)d_out;
    float* q   = (float*)d_ws;          // 2 * B * 512 floats = 32 KB

    int B = in_sizes[0];                         // 8
    int N = in_sizes[2] / (2 * EMB_DIM);         // 30000

    int qthreads = B * EMB_DIM;
    query_kernel<<<(qthreads + 255) / 256, 256, 0, stream>>>(
        all_h, all_r, eemb, remb, q, B);

    // 512 blocks * 4 waves = 2048 waves; ~15 entities each, grid-stride.
    score_kernel<<<512, 256, 0, stream>>>(eemb, q, out, N);
}

// Round 2
// 191.168 us; speedup vs baseline: 1.5184x; 1.5184x over previous
//
#include <hip/hip_runtime.h>
#include <math.h>

#define EMB_DIM 512
#define N_Q 8
#define GAMMA_F 12.0f

// ---------------------------------------------------------------------------
// Fused RotatE scoring kernel.
// Phase 1: every block computes the 8 rotated queries into LDS (redundant
//          across blocks, ~16 sincos/thread — trivial).
// Phase 2: each lane loads its query fragment: for all 8 queries b, the
//          float4 covering d = 4*lane..4*lane+3 of chunk A (d 0..255) and
//          chunk B (d 256..511), re and im. 128 VGPRs, loaded once.
// Phase 3: one wave per entity (grid-stride). Row loads are fully
//          coalesced: lane l reads floats 4l..4l+3 of each 256-float
//          chunk -> 4 x global_load_dwordx4 @ 1024 distinct bytes/wave.
//          Next row is prefetched into registers before computing current.
//          Per entity, lane computes partial dist for all 8 queries over
//          its 8 dims, then a transposing butterfly reduction leaves the
//          total for query b on lanes with (lane&7)==b.
// ---------------------------------------------------------------------------
__global__ __launch_bounds__(256, 2) void rotate_fused_kernel(
    const int* __restrict__ all_h,
    const int* __restrict__ all_r,
    const float* __restrict__ eemb,
    const float* __restrict__ remb,
    float* __restrict__ out,
    int N)
{
    __shared__ float lq[2 * N_Q * EMB_DIM];   // 32 KB: re_e[4096], im_e[4096]

    const int tid = threadIdx.x;

    // ---- Phase 1: rotated queries into LDS ----
    const float SCALE = (float)(M_PI * (double)EMB_DIM / 14.0);  // pi / (range/pi)
    #pragma unroll
    for (int k = 0; k < 16; ++k) {
        int p = tid + 256 * k;              // p = b*512 + j
        int b = p >> 9;
        int j = p & (EMB_DIM - 1);
        int h = all_h[b];
        int r = all_r[b];
        float re_h = eemb[(size_t)h * (2 * EMB_DIM) + j];
        float im_h = eemb[(size_t)h * (2 * EMB_DIM) + EMB_DIM + j];
        float phase = remb[r * EMB_DIM + j] * SCALE;
        float s, c;
        sincosf(phase, &s, &c);
        lq[p]                 = re_h * c - im_h * s;
        lq[N_Q * EMB_DIM + p] = re_h * s + im_h * c;
    }
    __syncthreads();

    const int lane = tid & 63;

    // ---- Phase 2: per-lane query fragments (all 8 queries, 8 dims each) ----
    float4 qrA[8], qrB[8], qiA[8], qiB[8];
    #pragma unroll
    for (int b = 0; b < 8; ++b) {
        const float* qb = lq + b * EMB_DIM + 4 * lane;
        qrA[b] = *(const float4*)(qb);
        qrB[b] = *(const float4*)(qb + 256);
        qiA[b] = *(const float4*)(qb + N_Q * EMB_DIM);
        qiB[b] = *(const float4*)(qb + N_Q * EMB_DIM + 256);
    }

    // ---- Phase 3: grid-stride over entities, one wave per entity ----
    const int wid = tid >> 6;
    int n = blockIdx.x * 4 + wid;
    const int nw = gridDim.x * 4;
    if (n >= N) return;

    const float* base = eemb + 4 * lane;

    float4 rA, rB, iA, iB, nrA, nrB, niA, niB;
    {
        const float* row = base + (size_t)n * (2 * EMB_DIM);
        rA = *(const float4*)(row);
        rB = *(const float4*)(row + 256);
        iA = *(const float4*)(row + 512);
        iB = *(const float4*)(row + 768);
    }

    while (true) {
        int nn = n + nw;
        bool more = nn < N;
        if (more) {
            const float* row = base + (size_t)nn * (2 * EMB_DIM);
            nrA = *(const float4*)(row);
            nrB = *(const float4*)(row + 256);
            niA = *(const float4*)(row + 512);
            niB = *(const float4*)(row + 768);
        }

        float acc[8];
        #pragma unroll
        for (int b = 0; b < 8; ++b) {
            float s = 0.f, dx, dy;
            dx = qrA[b].x - rA.x; dy = qiA[b].x - iA.x; s += __builtin_amdgcn_sqrtf(fmaf(dx, dx, dy * dy));
            dx = qrA[b].y - rA.y; dy = qiA[b].y - iA.y; s += __builtin_amdgcn_sqrtf(fmaf(dx, dx, dy * dy));
            dx = qrA[b].z - rA.z; dy = qiA[b].z - iA.z; s += __builtin_amdgcn_sqrtf(fmaf(dx, dx, dy * dy));
            dx = qrA[b].w - rA.w; dy = qiA[b].w - iA.w; s += __builtin_amdgcn_sqrtf(fmaf(dx, dx, dy * dy));
            dx = qrB[b].x - rB.x; dy = qiB[b].x - iB.x; s += __builtin_amdgcn_sqrtf(fmaf(dx, dx, dy * dy));
            dx = qrB[b].y - rB.y; dy = qiB[b].y - iB.y; s += __builtin_amdgcn_sqrtf(fmaf(dx, dx, dy * dy));
            dx = qrB[b].z - rB.z; dy = qiB[b].z - iB.z; s += __builtin_amdgcn_sqrtf(fmaf(dx, dx, dy * dy));
            dx = qrB[b].w - rB.w; dy = qiB[b].w - iB.w; s += __builtin_amdgcn_sqrtf(fmaf(dx, dx, dy * dy));
            acc[b] = s;
        }

        // ---- Transposing butterfly: 8 values x 64 lanes -> value b on lanes
        // with (lane&7)==b.  Stages mask 1,2,4 select-and-swap; 8,16,32 plain.
        const bool p1 = lane & 1;
        float r0, r1, r2, r3;
        {
            float x, z;
            x = p1 ? acc[1] : acc[0]; z = p1 ? acc[0] : acc[1]; r0 = x + __shfl_xor(z, 1);
            x = p1 ? acc[3] : acc[2]; z = p1 ? acc[2] : acc[3]; r1 = x + __shfl_xor(z, 1);
            x = p1 ? acc[5] : acc[4]; z = p1 ? acc[4] : acc[5]; r2 = x + __shfl_xor(z, 1);
            x = p1 ? acc[7] : acc[6]; z = p1 ? acc[6] : acc[7]; r3 = x + __shfl_xor(z, 1);
        }
        const bool p2 = lane & 2;
        float t0, t1;
        {
            float x, z;
            x = p2 ? r1 : r0; z = p2 ? r0 : r1; t0 = x + __shfl_xor(z, 2);
            x = p2 ? r3 : r2; z = p2 ? r2 : r3; t1 = x + __shfl_xor(z, 2);
        }
        const bool p3 = lane & 4;
        float u;
        {
            float x, z;
            x = p3 ? t1 : t0; z = p3 ? t0 : t1; u = x + __shfl_xor(z, 4);
        }
        u += __shfl_xor(u, 8);
        u += __shfl_xor(u, 16);
        u += __shfl_xor(u, 32);

        if (lane < 8) out[(size_t)lane * N + n] = GAMMA_F - u;

        if (!more) break;
        n = nn;
        rA = nrA; rB = nrB; iA = niA; iB = niB;
    }
}

extern "C" void kernel_launch(void* const* d_in, const int* in_sizes, int n_in,
                              void* d_out, int out_size, void* d_ws, size_t ws_size,
                              hipStream_t stream) {
    const int*   all_h = (const int*)d_in[0];
    const int*   all_r = (const int*)d_in[1];
    const float* eemb  = (const float*)d_in[2];
    const float* remb  = (const float*)d_in[3];
    float* out = (float*)d_out;

    int N = in_sizes[2] / (2 * EMB_DIM);   // 30000

    // 512 blocks x 4 waves = 2048 waves, all co-resident at 2 blocks/CU.
    rotate_fused_kernel<<<512, 256, 0, stream>>>(all_h, all_r, eemb, remb, out, N);
}

// Round 3
// 184.753 us; speedup vs baseline: 1.5711x; 1.0347x over previous
//
#include <hip/hip_runtime.h>
#include <math.h>

#define EMB_DIM 512
#define N_Q 8
#define GAMMA_F 12.0f

// ---------------------------------------------------------------------------
// Fused RotatE scoring, half-row-per-wave version.
//
// Phase 1: every block computes the 8 rotated queries into LDS (redundant
//          across blocks; __sincosf keeps it ~1 us).
// Phase 2: wave w (of 4 per block) owns half h = w&1 of a row and entity
//          slot e = w>>1. Lane l holds the q fragment for d-range
//          [h*256 + 4l, h*256 + 4l+4) for all 8 queries: 64 VGPRs.
// Phase 3: block processes 2 entities per iteration (waves {0,1} -> n,
//          waves {2,3} -> n+1), grid-stride 2*gridDim. Row loads fully
//          coalesced (2 x dwordx4 @ 1 KB/wave), next iteration prefetched.
//          Intra-wave transposing butterfly -> 8 query sums on lanes 0..7;
//          cross-wave combine via double-buffered LDS, ONE barrier per
//          iteration (per 2 entities).
// Occupancy: ~110 VGPR, launch_bounds(256,4) -> 4 blocks/CU, 16 waves/CU.
// ---------------------------------------------------------------------------
__global__ __launch_bounds__(256, 4) void rotate_fused_kernel(
    const int* __restrict__ all_h,
    const int* __restrict__ all_r,
    const float* __restrict__ eemb,
    const float* __restrict__ remb,
    float* __restrict__ out,
    int N)
{
    __shared__ float lq[2 * N_Q * EMB_DIM];   // 32 KB: re_e[4096] | im_e[4096]
    __shared__ float part[2][4][N_Q];         // [parity][wave][query]

    const int tid = threadIdx.x;

    // ---- Phase 1: rotated queries into LDS ----
    const float SCALE = (float)(M_PI * (double)EMB_DIM / 14.0);
    #pragma unroll
    for (int k = 0; k < 16; ++k) {
        int p = tid + 256 * k;              // p = b*512 + j
        int b = p >> 9;
        int j = p & (EMB_DIM - 1);
        int h = all_h[b];
        int r = all_r[b];
        float re_h = eemb[(size_t)h * (2 * EMB_DIM) + j];
        float im_h = eemb[(size_t)h * (2 * EMB_DIM) + EMB_DIM + j];
        float phase = remb[r * EMB_DIM + j] * SCALE;
        float s, c;
        __sincosf(phase, &s, &c);
        lq[p]                 = re_h * c - im_h * s;
        lq[N_Q * EMB_DIM + p] = re_h * s + im_h * c;
    }
    __syncthreads();

    const int lane = tid & 63;
    const int wid  = tid >> 6;
    const int half = wid & 1;     // which half-row this wave covers
    const int eoff = wid >> 1;    // which entity of the block's pair

    // ---- Phase 2: per-lane query fragments (8 queries x 4 complex) ----
    float4 qr[N_Q], qi[N_Q];
    #pragma unroll
    for (int b = 0; b < N_Q; ++b) {
        const float* qb = lq + b * EMB_DIM + half * 256 + 4 * lane;
        qr[b] = *(const float4*)(qb);
        qi[b] = *(const float4*)(qb + N_Q * EMB_DIM);
    }

    // ---- Phase 3: grid-stride, 2 entities per block per iteration ----
    const int base0  = blockIdx.x * 2;
    const int stride = gridDim.x * 2;
    const int iters  = (N - base0 + stride - 1) / stride;   // uniform in block

    // lane's slice of the re / im halves of a row
    const float* base_re = eemb + half * 256 + 4 * lane;
    const float* base_im = base_re + EMB_DIM;

    float4 r0, i0, nr, ni;
    {
        int n = base0 + eoff;
        int nc = (n < N) ? n : 0;
        const float* p = base_re + (size_t)nc * (2 * EMB_DIM);
        r0 = *(const float4*)(p);
        i0 = *(const float4*)(p + EMB_DIM);
    }

    for (int it = 0; it < iters; ++it) {
        int n  = base0 + eoff + it * stride;
        // prefetch next iteration's half-row
        {
            int n2 = n + stride;
            int nc = (n2 < N) ? n2 : 0;
            const float* p = base_re + (size_t)nc * (2 * EMB_DIM);
            nr = *(const float4*)(p);
            ni = *(const float4*)(p + EMB_DIM);
        }

        float acc[N_Q];
        #pragma unroll
        for (int b = 0; b < N_Q; ++b) {
            float s = 0.f, dx, dy;
            dx = qr[b].x - r0.x; dy = qi[b].x - i0.x; s += __builtin_amdgcn_sqrtf(fmaf(dx, dx, dy * dy));
            dx = qr[b].y - r0.y; dy = qi[b].y - i0.y; s += __builtin_amdgcn_sqrtf(fmaf(dx, dx, dy * dy));
            dx = qr[b].z - r0.z; dy = qi[b].z - i0.z; s += __builtin_amdgcn_sqrtf(fmaf(dx, dx, dy * dy));
            dx = qr[b].w - r0.w; dy = qi[b].w - i0.w; s += __builtin_amdgcn_sqrtf(fmaf(dx, dx, dy * dy));
            acc[b] = s;
        }

        // ---- Transposing butterfly: value for query (lane&7) ends on all
        // groups; lanes 0..7 hold the 8 query sums for this half-row.
        const bool p1 = lane & 1;
        float u0, u1, u2, u3;
        {
            float x, z;
            x = p1 ? acc[1] : acc[0]; z = p1 ? acc[0] : acc[1]; u0 = x + __shfl_xor(z, 1);
            x = p1 ? acc[3] : acc[2]; z = p1 ? acc[2] : acc[3]; u1 = x + __shfl_xor(z, 1);
            x = p1 ? acc[5] : acc[4]; z = p1 ? acc[4] : acc[5]; u2 = x + __shfl_xor(z, 1);
            x = p1 ? acc[7] : acc[6]; z = p1 ? acc[6] : acc[7]; u3 = x + __shfl_xor(z, 1);
        }
        const bool p2 = lane & 2;
        float t0, t1;
        {
            float x, z;
            x = p2 ? u1 : u0; z = p2 ? u0 : u1; t0 = x + __shfl_xor(z, 2);
            x = p2 ? u3 : u2; z = p2 ? u2 : u3; t1 = x + __shfl_xor(z, 2);
        }
        const bool p3 = lane & 4;
        float u;
        {
            float x, z;
            x = p3 ? t1 : t0; z = p3 ? t0 : t1; u = x + __shfl_xor(z, 4);
        }
        u += __shfl_xor(u, 8);
        u += __shfl_xor(u, 16);
        u += __shfl_xor(u, 32);

        if (lane < N_Q) part[it & 1][wid][lane] = u;
        __syncthreads();

        // wave 0, lanes 0..15: combine the two half-row partials and store
        if (tid < 2 * N_Q) {
            int e = tid >> 3;          // entity slot 0/1
            int b = tid & 7;           // query
            int ns = base0 + e + it * stride;
            if (ns < N) {
                float v = part[it & 1][2 * e][b] + part[it & 1][2 * e + 1][b];
                out[(size_t)b * N + ns] = GAMMA_F - v;
            }
        }

        r0 = nr; i0 = ni;
    }
}

extern "C" void kernel_launch(void* const* d_in, const int* in_sizes, int n_in,
                              void* d_out, int out_size, void* d_ws, size_t ws_size,
                              hipStream_t stream) {
    const int*   all_h = (const int*)d_in[0];
    const int*   all_r = (const int*)d_in[1];
    const float* eemb  = (const float*)d_in[2];
    const float* remb  = (const float*)d_in[3];
    float* out = (float*)d_out;

    int N = in_sizes[2] / (2 * EMB_DIM);   // 30000

    // 1024 blocks = 4 blocks/CU co-resident; 2 entities per block-iteration.
    rotate_fused_kernel<<<1024, 256, 0, stream>>>(all_h, all_r, eemb, remb, out, N);
}